// Round 3
// baseline (602.804 us; speedup 1.0000x reference)
//
#include <hip/hip_runtime.h>
#include <hip/hip_bf16.h>

#define AS1 __attribute__((address_space(1)))
#define AS3 __attribute__((address_space(3)))

typedef __attribute__((ext_vector_type(8))) short short8;
typedef __attribute__((ext_vector_type(4))) short short4v;
typedef __attribute__((ext_vector_type(4))) float f32x4;

constexpr int S_ = 2048;
constexpr int HID_ = 4096;
constexpr int NH = 32;       // q heads
constexpr int NKH = 8;       // kv heads
constexpr float EPS_ = 1e-5f;
constexpr float SCALE_ = 0.08838834764831845f;  // 128^-0.5

__device__ __forceinline__ short f2bf(float f) {
  __hip_bfloat16 h = __float2bfloat16(f);
  return *reinterpret_cast<short*>(&h);
}

// ---------------- fp32 -> bf16 cast (vectorized) ----------------
__global__ __launch_bounds__(256) void cast_bf16_kernel(const float4* __restrict__ src,
                                                        short4v* __restrict__ dst, int n4) {
  int i = blockIdx.x * 256 + threadIdx.x;
  if (i >= n4) return;
  float4 v = src[i];
  short4v o;
  o[0] = f2bf(v.x); o[1] = f2bf(v.y); o[2] = f2bf(v.z); o[3] = f2bf(v.w);
  dst[i] = o;
}

// ================= 256x256 8-phase bf16 GEMM (C = A * B^T) ==============
// BM=BN=256, BK=64, 512 thr = 8 waves (2 M x 4 N), per-wave out 128x64.
// LDS 128 KiB dynamic: [buf0: A 32K | B 32K][buf1: A | B], double-buffered.
// Swizzle: byte ^= ((row>>2)&1)<<5 (st_16x32), applied on pre-swizzled
// global source (linear LDS dest for global_load_lds) and on ds_read.
// Schedule per K-tile (4 phases = 4 C-quadrants, 16 MFMA each):
//   q0: ds_read A-frag 0-3 (both k) + B-frag 0-1 | stage | bar | MFMA | bar
//   q1: ds_read B-frag 2-3                        | stage | bar | MFMA | bar
//   q2: ds_read A-frag 4-7                        | stage | bar | MFMA | bar
//   q3: (no reads)                                | stage | bar | MFMA | vmcnt(2) | bar
// Stage h(p) = p+5 (p = tt*4+q), skipped while p<3; prologue stages Kt0+Kt1,
// vmcnt(8). Invariant: a region staged in phase p had all reads in <= p-1;
// vmcnt(2) at q3 forces the next tile's 4 half-tiles landed. Never vmcnt(0).
__global__ __launch_bounds__(512, 2) void gemm8_bt(const short* __restrict__ A,
                                                   const short* __restrict__ B,
                                                   float* __restrict__ C,
                                                   int M, int N, int K) {
  extern __shared__ __align__(16) char smem[];
  const int t = threadIdx.x, w = t >> 6, lane = t & 63;
  const int nbx = N >> 8;
  int wg = blockIdx.x;
  const int cpx = gridDim.x >> 3;               // grid % 8 == 0
  wg = (wg & 7) * cpx + (wg >> 3);              // XCD-chunked swizzle
  const int by = wg / nbx, bx = wg % nbx;
  const long m0 = (long)by << 8, n0 = (long)bx << 8;
  const int wr = w >> 2, wc = w & 3;
  const int l15 = lane & 15, l4 = lane >> 4;
  const int NT = K >> 6;                        // K-tiles (power of two here)

  f32x4 acc[8][4];
#pragma unroll
  for (int f = 0; f < 8; ++f)
#pragma unroll
    for (int g = 0; g < 4; ++g) acc[f][g] = (f32x4){0.f, 0.f, 0.f, 0.f};

  // stage one 16KB half-tile (2 global_load_lds per wave).
  // half: 0=A rows0-127, 1=A rows128-255, 2=B rows0-127, 3=B rows128-255
  auto STAGE = [&](int h) {
    int hm = h & (4 * NT - 1);
    int tt = hm >> 2, half = hm & 3;
    int buf = tt & 1;
    long k0 = (long)tt << 6;
    const short* src = (half < 2) ? A : B;
    long r0 = (half < 2) ? m0 : n0;
    char* lbase = smem + buf * 65536 + ((half >> 1) << 15) + ((half & 1) << 14);
#pragma unroll
    for (int j = 0; j < 2; ++j) {
      int row = ((half & 1) << 7) + j * 64 + w * 8 + (lane >> 3);
      int cs = (lane & 7) ^ (((row >> 2) & 1) << 1);   // inverse swizzle on src
      __builtin_amdgcn_global_load_lds(
          (const AS1 void*)(src + (r0 + row) * K + k0 + cs * 8),
          (AS3 void*)(lbase + j * 8192 + w * 1024 + lane * 16), 16, 0, 0);
    }
  };
  auto LDA = [&](int buf, int f, int s) -> short8 {
    int ra = wr * 128 + f * 16 + l15;
    int byte = (ra * 128 + s * 64 + l4 * 16) ^ (((ra >> 2) & 1) << 5);
    return *(const short8*)(smem + buf * 65536 + byte);
  };
  auto LDB = [&](int buf, int g, int s) -> short8 {
    int rb = wc * 64 + g * 16 + l15;
    int byte = (rb * 128 + s * 64 + l4 * 16) ^ (((rb >> 2) & 1) << 5);
    return *(const short8*)(smem + buf * 65536 + 32768 + byte);
  };

  // prologue: Kt0 -> buf0, Kt1 -> buf1
#pragma unroll
  for (int h = 0; h < 8; ++h) STAGE(h);
  asm volatile("s_waitcnt vmcnt(8)" ::: "memory");
  asm volatile("s_barrier" ::: "memory");

  short8 af[4][2], bf2[4][2];
  for (int tt = 0; tt < NT; ++tt) {
    const int buf = tt & 1;
    const int p = tt * 4;
    // ---------- phase q0: quadrant f0-3 x g0-1 ----------
#pragma unroll
    for (int f = 0; f < 4; ++f) { af[f][0] = LDA(buf, f, 0); af[f][1] = LDA(buf, f, 1); }
#pragma unroll
    for (int g = 0; g < 2; ++g) { bf2[g][0] = LDB(buf, g, 0); bf2[g][1] = LDB(buf, g, 1); }
    if (tt) STAGE(p + 5);
    asm volatile("s_barrier" ::: "memory");
    __builtin_amdgcn_s_setprio(1);
#pragma unroll
    for (int f = 0; f < 4; ++f)
#pragma unroll
      for (int g = 0; g < 2; ++g) {
        acc[f][g] = __builtin_amdgcn_mfma_f32_16x16x32_bf16(af[f][0], bf2[g][0], acc[f][g], 0, 0, 0);
        acc[f][g] = __builtin_amdgcn_mfma_f32_16x16x32_bf16(af[f][1], bf2[g][1], acc[f][g], 0, 0, 0);
      }
    __builtin_amdgcn_s_setprio(0);
    asm volatile("s_barrier" ::: "memory");
    // ---------- phase q1: f0-3 x g2-3 ----------
#pragma unroll
    for (int g = 0; g < 2; ++g) { bf2[2 + g][0] = LDB(buf, 2 + g, 0); bf2[2 + g][1] = LDB(buf, 2 + g, 1); }
    if (tt) STAGE(p + 6);
    asm volatile("s_barrier" ::: "memory");
    __builtin_amdgcn_s_setprio(1);
#pragma unroll
    for (int f = 0; f < 4; ++f)
#pragma unroll
      for (int g = 0; g < 2; ++g) {
        acc[f][2 + g] = __builtin_amdgcn_mfma_f32_16x16x32_bf16(af[f][0], bf2[2 + g][0], acc[f][2 + g], 0, 0, 0);
        acc[f][2 + g] = __builtin_amdgcn_mfma_f32_16x16x32_bf16(af[f][1], bf2[2 + g][1], acc[f][2 + g], 0, 0, 0);
      }
    __builtin_amdgcn_s_setprio(0);
    asm volatile("s_barrier" ::: "memory");
    // ---------- phase q2: f4-7 x g0-1 ----------
#pragma unroll
    for (int f = 0; f < 4; ++f) { af[f][0] = LDA(buf, 4 + f, 0); af[f][1] = LDA(buf, 4 + f, 1); }
    if (tt) STAGE(p + 7);
    asm volatile("s_barrier" ::: "memory");
    __builtin_amdgcn_s_setprio(1);
#pragma unroll
    for (int f = 0; f < 4; ++f)
#pragma unroll
      for (int g = 0; g < 2; ++g) {
        acc[4 + f][g] = __builtin_amdgcn_mfma_f32_16x16x32_bf16(af[f][0], bf2[g][0], acc[4 + f][g], 0, 0, 0);
        acc[4 + f][g] = __builtin_amdgcn_mfma_f32_16x16x32_bf16(af[f][1], bf2[g][1], acc[4 + f][g], 0, 0, 0);
      }
    __builtin_amdgcn_s_setprio(0);
    asm volatile("s_barrier" ::: "memory");
    // ---------- phase q3: f4-7 x g2-3 ----------
    STAGE(p + 8);
    asm volatile("s_barrier" ::: "memory");
    __builtin_amdgcn_s_setprio(1);
#pragma unroll
    for (int f = 0; f < 4; ++f)
#pragma unroll
      for (int g = 0; g < 2; ++g) {
        acc[4 + f][2 + g] = __builtin_amdgcn_mfma_f32_16x16x32_bf16(af[f][0], bf2[2 + g][0], acc[4 + f][2 + g], 0, 0, 0);
        acc[4 + f][2 + g] = __builtin_amdgcn_mfma_f32_16x16x32_bf16(af[f][1], bf2[2 + g][1], acc[4 + f][2 + g], 0, 0, 0);
      }
    __builtin_amdgcn_s_setprio(0);
    asm volatile("s_waitcnt vmcnt(2)" ::: "memory");
    asm volatile("s_barrier" ::: "memory");
  }
  // epilogue
#pragma unroll
  for (int f = 0; f < 8; ++f)
#pragma unroll
    for (int g = 0; g < 4; ++g)
#pragma unroll
      for (int r = 0; r < 4; ++r) {
        long m = m0 + wr * 128 + f * 16 + l4 * 4 + r;
        long n = n0 + wc * 64 + g * 16 + l15;
        C[m * N + n] = acc[f][g][r];
      }
}

// ---------------- RMS norm + partial RoPE (Q and K only) --------------
__global__ __launch_bounds__(256) void normrope_kernel(const float* __restrict__ QKV,
    const int* __restrict__ pos_ids, const float* __restrict__ qw,
    const float* __restrict__ kw,
    short* __restrict__ Qn, short* __restrict__ Kn) {
  const int lane = threadIdx.x & 63;
  const long row = (long)blockIdx.x * 4 + (threadIdx.x >> 6);
  const long NQ = (long)S_ * NH;
  const float* src;
  short* dst;
  const float* wv;
  int s;
  float scl = 1.f;
  if (row < NQ) {
    s = (int)(row >> 5); int h = (int)(row & 31);
    src = QKV + (long)s * 6144 + h * 128;
    dst = Qn + ((long)h * S_ + s) * 128;
    wv = qw; scl = SCALE_;
  } else {
    long r2 = row - NQ; s = (int)(r2 >> 3); int kh = (int)(r2 & 7);
    src = QKV + (long)s * 6144 + 4096 + kh * 128;
    dst = Kn + ((long)kh * S_ + s) * 128;
    wv = kw;
  }
  float x0 = src[lane], x1 = src[lane + 64];
  float ss = x0 * x0 + x1 * x1;
#pragma unroll
  for (int m = 1; m < 64; m <<= 1) ss += __shfl_xor(ss, m);
  float inv = rsqrtf(ss * (1.f / 128.f) + EPS_);
  x0 = x0 * inv * (wv[lane] + 1.f);
  x1 = x1 * inv * (wv[lane + 64] + 1.f);
  int pos = pos_ids[s];
  int i = lane & 31;
  float invf = expf(-logf(10000.f) * ((float)(2 * i) / 64.f));
  float f = (float)pos * invf;
  float c = cosf(f), sn = sinf(f);
  float p = __shfl_xor(x0, 32);
  x0 = (lane < 32) ? (x0 * c - p * sn) : (x0 * c + p * sn);
  dst[lane] = f2bf(x0 * scl);
  dst[lane + 64] = f2bf(x1 * scl);
}

// ---------------- V transpose: QKVf V-cols -> Vt[kh][128][S] bf16 ------
__global__ __launch_bounds__(256) void vtrans_kernel(const float* __restrict__ QKV,
                                                     short* __restrict__ Vt) {
  __shared__ __align__(16) float lt[64][68];
  const int t = threadIdx.x;
  const int s0 = blockIdx.x * 64, d0 = blockIdx.y * 64, kh = blockIdx.z;
  const float* src = QKV + (long)s0 * 6144 + 5120 + kh * 128 + d0;
#pragma unroll
  for (int i = 0; i < 4; ++i) {
    int idx = t + i * 256;
    int r = idx >> 4, c4 = (idx & 15) * 4;
    float4 v = *(const float4*)(src + (long)r * 6144 + c4);
    *(float4*)&lt[r][c4] = v;
  }
  __syncthreads();
  int d = t >> 2, seg = (t & 3) * 16;
  short* dst = Vt + ((long)kh * 128 + d0 + d) * S_ + s0 + seg;
  short8 a, b2;
#pragma unroll
  for (int j = 0; j < 8; ++j) a[j] = f2bf(lt[seg + j][d]);
#pragma unroll
  for (int j = 0; j < 8; ++j) b2[j] = f2bf(lt[seg + 8 + j][d]);
  *(short8*)dst = a;
  *(short8*)(dst + 8) = b2;
}

// ---------------- causal flash attention, GQA 4:1 ----------------------
__global__ __launch_bounds__(512, 2) void attn_kernel(const short* __restrict__ Qn,
    const short* __restrict__ Kn, const short* __restrict__ Vt,
    short* __restrict__ O) {
  __shared__ __align__(16) short Ks[64 * 128];
  __shared__ __align__(16) short Vs[128 * 64];
  __shared__ __align__(16) short Ps[8][16 * 64];
  const int t = threadIdx.x, w = t >> 6, lane = t & 63;
  const int b = blockIdx.x;
  const int h = b & 31, qt = 15 - (b >> 5);
  const int kh = h >> 2;
  const int q0 = qt * 128;
  const int l15 = lane & 15, lk = (lane >> 4) * 8;

  short8 qf[4];
  {
    const short* Qh = Qn + ((long)h * S_ + q0 + w * 16) * 128;
#pragma unroll
    for (int ks = 0; ks < 4; ++ks)
      qf[ks] = *(const short8*)(Qh + l15 * 128 + ks * 32 + lk);
  }
  f32x4 o[8];
#pragma unroll
  for (int nf = 0; nf < 8; ++nf) o[nf] = (f32x4){0.f, 0.f, 0.f, 0.f};
  float mrun[4], lrun[4];
#pragma unroll
  for (int r = 0; r < 4; ++r) { mrun[r] = -1e30f; lrun[r] = 0.f; }

  const short* Khp = Kn + (long)kh * S_ * 128;
  const short* Vtp = Vt + (long)kh * 128 * S_;

  const int krr = w * 8 + (lane >> 4);
  const int kc = lane & 15;
  const int vdd = w * 16 + (lane >> 3);
  const int vc = lane & 7;
  char* pw = (char*)Ps[w];
  const int mrow = (lane >> 4) * 4;

  for (int kv0 = 0; kv0 < q0 + 128; kv0 += 64) {
#pragma unroll
    for (int j = 0; j < 2; ++j) {
      int rr = krr + j * 4;
      __builtin_amdgcn_global_load_lds(
          (const AS1 void*)(Khp + (long)(kv0 + rr) * 128 + ((kc ^ (rr & 7)) * 8)),
          (AS3 void*)(Ks + (w * 8 + j * 4) * 128 + lane * 8), 16, 0, 0);
    }
#pragma unroll
    for (int j = 0; j < 2; ++j) {
      int d = vdd + j * 8;
      __builtin_amdgcn_global_load_lds(
          (const AS1 void*)(Vtp + (long)d * S_ + kv0 + ((vc ^ (d & 7)) * 8)),
          (AS3 void*)(Vs + (w * 16 + j * 8) * 64 + lane * 8), 16, 0, 0);
    }
    __syncthreads();

    const bool active = (kv0 <= q0 + w * 16 + 15);
    if (active) {
      f32x4 sc[4];
#pragma unroll
      for (int ni = 0; ni < 4; ++ni) sc[ni] = (f32x4){0.f, 0.f, 0.f, 0.f};
#pragma unroll
      for (int ks = 0; ks < 4; ++ks)
#pragma unroll
        for (int ni = 0; ni < 4; ++ni) {
          int row = ni * 16 + l15;
          int bb = row * 256 + (ks * 32 + lk) * 2; bb ^= (row & 7) << 4;
          short8 kf = *(const short8*)((const char*)Ks + bb);
          sc[ni] = __builtin_amdgcn_mfma_f32_16x16x32_bf16(qf[ks], kf, sc[ni], 0, 0, 0);
        }
      if (kv0 + 64 > q0 + w * 16) {
#pragma unroll
        for (int ni = 0; ni < 4; ++ni)
#pragma unroll
          for (int r = 0; r < 4; ++r) {
            int qm = q0 + w * 16 + mrow + r;
            int kcol = kv0 + ni * 16 + l15;
            if (kcol > qm) sc[ni][r] = -1e30f;
          }
      }
      short pb[4][4];
#pragma unroll
      for (int r = 0; r < 4; ++r) {
        float mx = fmaxf(fmaxf(sc[0][r], sc[1][r]), fmaxf(sc[2][r], sc[3][r]));
        mx = fmaxf(mx, __shfl_xor(mx, 1));
        mx = fmaxf(mx, __shfl_xor(mx, 2));
        mx = fmaxf(mx, __shfl_xor(mx, 4));
        mx = fmaxf(mx, __shfl_xor(mx, 8));
        float mnew = fmaxf(mrun[r], mx);
        float scale = expf(mrun[r] - mnew);
        mrun[r] = mnew;
        float ssum = 0.f;
#pragma unroll
        for (int ni = 0; ni < 4; ++ni) {
          float p = expf(sc[ni][r] - mnew);
          ssum += p;
          pb[ni][r] = f2bf(p);
        }
        ssum += __shfl_xor(ssum, 1);
        ssum += __shfl_xor(ssum, 2);
        ssum += __shfl_xor(ssum, 4);
        ssum += __shfl_xor(ssum, 8);
        lrun[r] = lrun[r] * scale + ssum;
#pragma unroll
        for (int nf = 0; nf < 8; ++nf) o[nf][r] *= scale;
      }
#pragma unroll
      for (int ni = 0; ni < 4; ++ni)
#pragma unroll
        for (int r = 0; r < 4; ++r) {
          int m = mrow + r;
          int bb = m * 128 + (ni * 16 + l15) * 2; bb ^= (m & 7) << 4;
          *(short*)(pw + bb) = pb[ni][r];
        }
#pragma unroll
      for (int ks2 = 0; ks2 < 2; ++ks2) {
        int bp = l15 * 128 + (ks2 * 32 + lk) * 2; bp ^= (l15 & 7) << 4;
        short8 pf = *(const short8*)(pw + bp);
#pragma unroll
        for (int nf = 0; nf < 8; ++nf) {
          int bv = (nf * 16 + l15) * 128 + (ks2 * 32 + lk) * 2; bv ^= (l15 & 7) << 4;
          short8 vf = *(const short8*)((const char*)Vs + bv);
          o[nf] = __builtin_amdgcn_mfma_f32_16x16x32_bf16(pf, vf, o[nf], 0, 0, 0);
        }
      }
    }
    __syncthreads();
  }
#pragma unroll
  for (int r = 0; r < 4; ++r) {
    float invl = 1.f / lrun[r];
    int m = q0 + w * 16 + mrow + r;
#pragma unroll
    for (int nf = 0; nf < 8; ++nf)
      O[(long)m * 4096 + h * 128 + nf * 16 + l15] = f2bf(o[nf][r] * invl);
  }
}

// ---------------- launch -----------------------------------------------
extern "C" void kernel_launch(void* const* d_in, const int* in_sizes, int n_in,
                              void* d_out, int out_size, void* d_ws, size_t ws_size,
                              hipStream_t stream) {
  const float* hidden = (const float*)d_in[0];
  const float* Wq = (const float*)d_in[1];
  const float* Wk = (const float*)d_in[2];
  const float* Wv = (const float*)d_in[3];
  const float* Wo = (const float*)d_in[4];
  const float* qw = (const float*)d_in[5];
  const float* kw = (const float*)d_in[6];
  const int* pos = (const int*)d_in[7];
  float* out = (float*)d_out;

  char* ws = (char*)d_ws;
  short* hid_bf  = (short*)(ws + 0);              // 16 MB (dead after GEMM1)
  short* Wqkv_bf = (short*)(ws + 16777216L);      // 48 MB
  short* Wo_bf   = (short*)(ws + 67108864L);      // 32 MB
  float* QKVf    = (float*)(ws + 100663296L);     // 48 MB
  short* Qn      = (short*)(ws + 150994944L);     // 16 MB
  short* Kn      = (short*)(ws + 167772160L);     // 4 MB
  short* Vt      = (short*)(ws + 171966464L);     // 4 MB
  short* AO      = hid_bf;                        // alias

  (void)hipFuncSetAttribute((const void*)gemm8_bt,
                            hipFuncAttributeMaxDynamicSharedMemorySize, 131072);

  auto cast = [&](const float* s_, short* d_, long n) {
    int n4 = (int)(n / 4);
    cast_bf16_kernel<<<(n4 + 255) / 256, 256, 0, stream>>>((const float4*)s_, (short4v*)d_, n4);
  };
  cast(hidden, hid_bf, (long)S_ * HID_);
  cast(Wq, Wqkv_bf, (long)4096 * 4096);
  cast(Wk, Wqkv_bf + (long)4096 * 4096, (long)1024 * 4096);
  cast(Wv, Wqkv_bf + (long)5120 * 4096, (long)1024 * 4096);
  cast(Wo, Wo_bf, (long)4096 * 4096);

  // QKV = hidden @ [Wq;Wk;Wv]^T : M=2048, N=6144, K=4096 -> 192 blocks
  gemm8_bt<<<dim3(192), 512, 131072, stream>>>(hid_bf, Wqkv_bf, QKVf, S_, 6144, HID_);

  normrope_kernel<<<(S_ * (NH + NKH)) / 4, 256, 0, stream>>>(QKVf, pos, qw, kw, Qn, Kn);
  vtrans_kernel<<<dim3(S_ / 64, 2, NKH), 256, 0, stream>>>(QKVf, Vt);
  attn_kernel<<<dim3(512), 512, 0, stream>>>(Qn, Kn, Vt, AO);

  // out = AO @ Wo^T : M=2048, N=4096, K=4096 -> 128 blocks
  gemm8_bt<<<dim3(128), 512, 131072, stream>>>(AO, Wo_bf, out, S_, HID_, HID_);
}

// Round 4
// 524.438 us; speedup vs baseline: 1.1494x; 1.1494x over previous
//
#include <hip/hip_runtime.h>
#include <hip/hip_bf16.h>

#define AS1 __attribute__((address_space(1)))
#define AS3 __attribute__((address_space(3)))

typedef __attribute__((ext_vector_type(8))) short short8;
typedef __attribute__((ext_vector_type(4))) short short4v;
typedef __attribute__((ext_vector_type(4))) float f32x4;

constexpr int S_ = 2048;
constexpr int HID_ = 4096;
constexpr int NH = 32;       // q heads
constexpr int NKH = 8;       // kv heads
constexpr float EPS_ = 1e-5f;
constexpr float SCALE_ = 0.08838834764831845f;  // 128^-0.5

__device__ __forceinline__ short f2bf(float f) {
  __hip_bfloat16 h = __float2bfloat16(f);
  return *reinterpret_cast<short*>(&h);
}

// ---------------- fp32 -> bf16 cast (vectorized) ----------------
__global__ __launch_bounds__(256) void cast_bf16_kernel(const float4* __restrict__ src,
                                                        short4v* __restrict__ dst, int n4) {
  int i = blockIdx.x * 256 + threadIdx.x;
  if (i >= n4) return;
  float4 v = src[i];
  short4v o;
  o[0] = f2bf(v.x); o[1] = f2bf(v.y); o[2] = f2bf(v.z); o[3] = f2bf(v.w);
  dst[i] = o;
}

// ================= 256 x (G*64) 8-phase bf16 GEMM (C = A * B^T) =========
// BM=256, BN=G*64 (G=3 -> 192, G=2 -> 128), BK=64, 512 thr = 8 waves (2Mx4N),
// per-wave out 128 x G*16. LDS double-buffered, dynamic.
// Swizzle (3-bit): stored 16B-chunk = logical_chunk ^ (row & 7); applied as
// pre-swizzled GLOBAL source (linear LDS dest for global_load_lds) and the
// same XOR on ds_read byte addr. 16 lanes reading 16 consecutive rows at one
// chunk now span all 8 chunk slots twice -> 2-way, which is free (m136).
// Stage units per K-tile: {A0(2 ld), A1(2 ld), B0..B_{G-1}(1 ld each)}.
// Schedule (quadrant phases; every phase = reads|stage|bar|MFMA|bar):
//   q0: rd af[0-3][k0,k1] + bf[0..GH-1]      | stage A1(t+1)
//   q1: rd bf[GH..G-1]                        | stage B0..B_{G-2}(t+1)
//   q2: rd af[4-7]                            | stage B_{G-1}(t+1)
//   q3: (no reads)                            | stage A0(t+2)  [same buf: safe,
//        all ds_reads of this buf completed before q3's leading barrier]
//   q3 tail: vmcnt(2) -> oldest loads = ALL of tile t+1 landed; never vmcnt(0).
template <int G>
__global__ __launch_bounds__(512, 2) void gemm8_bt(const short* __restrict__ A,
                                                   const short* __restrict__ B,
                                                   float* __restrict__ C,
                                                   int M, int N, int K) {
  constexpr int BN = G * 64;
  constexpr int BUFSZ = 32768 + G * 8192;
  constexpr int GH = (G + 1) / 2;
  extern __shared__ __align__(16) char smem[];
  const int t = threadIdx.x, w = t >> 6, lane = t & 63;
  const int nbx = N / BN;
  int wg = blockIdx.x;
  const int cpx = gridDim.x >> 3;               // grid % 8 == 0
  wg = (wg & 7) * cpx + (wg >> 3);              // XCD-chunked swizzle
  const int by = wg / nbx, bx = wg % nbx;
  const long m0 = (long)by * 256, n0 = (long)bx * BN;
  const int wr = w >> 2, wc = w & 3;
  const int l15 = lane & 15, l4 = lane >> 4;
  const int NT = K >> 6;                        // power of two here

  f32x4 acc[8][G];
#pragma unroll
  for (int f = 0; f < 8; ++f)
#pragma unroll
    for (int g = 0; g < G; ++g) acc[f][g] = (f32x4){0.f, 0.f, 0.f, 0.f};

  const int srow = w * 8 + (lane >> 3);         // 0..63 within a 64-row unit
  const int schunk = lane & 7;

  auto STAGE = [&](int tile, int unit) {
    int tb = tile & (NT - 1);
    long k0 = (long)tb << 6;
    char* base = smem + (tb & 1) * BUFSZ;
    if (unit < 2) {                             // A unit: 128 rows, 2 loads
#pragma unroll
      for (int j = 0; j < 2; ++j) {
        int row = unit * 128 + j * 64 + srow;
        int ch = schunk ^ (row & 7);
        __builtin_amdgcn_global_load_lds(
            (const AS1 void*)(A + (m0 + row) * K + k0 + ch * 8),
            (AS3 void*)(base + unit * 16384 + j * 8192 + w * 1024 + lane * 16), 16, 0, 0);
      }
    } else {                                    // B unit: 64 rows, 1 load
      int bj = unit - 2;
      int row = bj * 64 + srow;
      int ch = schunk ^ (row & 7);
      __builtin_amdgcn_global_load_lds(
          (const AS1 void*)(B + (n0 + row) * K + k0 + ch * 8),
          (AS3 void*)(base + 32768 + bj * 8192 + w * 1024 + lane * 16), 16, 0, 0);
    }
  };
  auto LDA = [&](int buf, int f, int s) -> short8 {
    int ra = wr * 128 + f * 16 + l15;
    int byte = ra * 128 + (((s << 2) + l4) ^ (ra & 7)) * 16;
    return *(const short8*)(smem + buf * BUFSZ + byte);
  };
  auto LDB = [&](int buf, int g, int s) -> short8 {
    int rb = wc * (G * 16) + g * 16 + l15;
    int byte = 32768 + rb * 128 + (((s << 2) + l4) ^ (rb & 7)) * 16;
    return *(const short8*)(smem + buf * BUFSZ + byte);
  };

  // prologue: tile0 fully + tile1 A0; leave tile1-A0's 2 loads outstanding
#pragma unroll
  for (int u = 0; u < 2 + G; ++u) STAGE(0, u);
  STAGE(1, 0);
  asm volatile("s_waitcnt vmcnt(2)" ::: "memory");
  asm volatile("s_barrier" ::: "memory");

  short8 af[4][2], bf2[G][2];
  for (int tt = 0; tt < NT; ++tt) {
    const int buf = tt & 1;
    // ---------- q0: f0-3 x g[0..GH) ----------
#pragma unroll
    for (int f = 0; f < 4; ++f) { af[f][0] = LDA(buf, f, 0); af[f][1] = LDA(buf, f, 1); }
#pragma unroll
    for (int g = 0; g < GH; ++g) { bf2[g][0] = LDB(buf, g, 0); bf2[g][1] = LDB(buf, g, 1); }
    STAGE(tt + 1, 1);
    asm volatile("s_barrier" ::: "memory");
    __builtin_amdgcn_s_setprio(1);
#pragma unroll
    for (int f = 0; f < 4; ++f)
#pragma unroll
      for (int g = 0; g < GH; ++g) {
        acc[f][g] = __builtin_amdgcn_mfma_f32_16x16x32_bf16(af[f][0], bf2[g][0], acc[f][g], 0, 0, 0);
        acc[f][g] = __builtin_amdgcn_mfma_f32_16x16x32_bf16(af[f][1], bf2[g][1], acc[f][g], 0, 0, 0);
      }
    __builtin_amdgcn_s_setprio(0);
    asm volatile("s_barrier" ::: "memory");
    // ---------- q1: f0-3 x g[GH..G) ----------
#pragma unroll
    for (int g = GH; g < G; ++g) { bf2[g][0] = LDB(buf, g, 0); bf2[g][1] = LDB(buf, g, 1); }
#pragma unroll
    for (int u = 2; u < G + 1; ++u) STAGE(tt + 1, u);      // B0..B_{G-2}
    asm volatile("s_barrier" ::: "memory");
    __builtin_amdgcn_s_setprio(1);
#pragma unroll
    for (int f = 0; f < 4; ++f)
#pragma unroll
      for (int g = GH; g < G; ++g) {
        acc[f][g] = __builtin_amdgcn_mfma_f32_16x16x32_bf16(af[f][0], bf2[g][0], acc[f][g], 0, 0, 0);
        acc[f][g] = __builtin_amdgcn_mfma_f32_16x16x32_bf16(af[f][1], bf2[g][1], acc[f][g], 0, 0, 0);
      }
    __builtin_amdgcn_s_setprio(0);
    asm volatile("s_barrier" ::: "memory");
    // ---------- q2: f4-7 x g[0..GH) ----------
#pragma unroll
    for (int f = 0; f < 4; ++f) { af[f][0] = LDA(buf, 4 + f, 0); af[f][1] = LDA(buf, 4 + f, 1); }
    STAGE(tt + 1, G + 1);                                  // B_{G-1}
    asm volatile("s_barrier" ::: "memory");
    __builtin_amdgcn_s_setprio(1);
#pragma unroll
    for (int f = 0; f < 4; ++f)
#pragma unroll
      for (int g = 0; g < GH; ++g) {
        acc[4 + f][g] = __builtin_amdgcn_mfma_f32_16x16x32_bf16(af[f][0], bf2[g][0], acc[4 + f][g], 0, 0, 0);
        acc[4 + f][g] = __builtin_amdgcn_mfma_f32_16x16x32_bf16(af[f][1], bf2[g][1], acc[4 + f][g], 0, 0, 0);
      }
    __builtin_amdgcn_s_setprio(0);
    asm volatile("s_barrier" ::: "memory");
    // ---------- q3: f4-7 x g[GH..G) ----------
    STAGE(tt + 2, 0);                                      // A0 of tile+2
    asm volatile("s_barrier" ::: "memory");
    __builtin_amdgcn_s_setprio(1);
#pragma unroll
    for (int f = 0; f < 4; ++f)
#pragma unroll
      for (int g = GH; g < G; ++g) {
        acc[4 + f][g] = __builtin_amdgcn_mfma_f32_16x16x32_bf16(af[f][0], bf2[g][0], acc[4 + f][g], 0, 0, 0);
        acc[4 + f][g] = __builtin_amdgcn_mfma_f32_16x16x32_bf16(af[f][1], bf2[g][1], acc[4 + f][g], 0, 0, 0);
      }
    __builtin_amdgcn_s_setprio(0);
    asm volatile("s_waitcnt vmcnt(2)" ::: "memory");
    asm volatile("s_barrier" ::: "memory");
  }
  // epilogue
#pragma unroll
  for (int f = 0; f < 8; ++f)
#pragma unroll
    for (int g = 0; g < G; ++g)
#pragma unroll
      for (int r = 0; r < 4; ++r) {
        long m = m0 + wr * 128 + f * 16 + l4 * 4 + r;
        long n = n0 + wc * (G * 16) + g * 16 + l15;
        C[m * N + n] = acc[f][g][r];
      }
}

// ---------------- RMS norm + partial RoPE (Q and K only) --------------
__global__ __launch_bounds__(256) void normrope_kernel(const float* __restrict__ QKV,
    const int* __restrict__ pos_ids, const float* __restrict__ qw,
    const float* __restrict__ kw,
    short* __restrict__ Qn, short* __restrict__ Kn) {
  const int lane = threadIdx.x & 63;
  const long row = (long)blockIdx.x * 4 + (threadIdx.x >> 6);
  const long NQ = (long)S_ * NH;
  const float* src;
  short* dst;
  const float* wv;
  int s;
  float scl = 1.f;
  if (row < NQ) {
    s = (int)(row >> 5); int h = (int)(row & 31);
    src = QKV + (long)s * 6144 + h * 128;
    dst = Qn + ((long)h * S_ + s) * 128;
    wv = qw; scl = SCALE_;
  } else {
    long r2 = row - NQ; s = (int)(r2 >> 3); int kh = (int)(r2 & 7);
    src = QKV + (long)s * 6144 + 4096 + kh * 128;
    dst = Kn + ((long)kh * S_ + s) * 128;
    wv = kw;
  }
  float x0 = src[lane], x1 = src[lane + 64];
  float ss = x0 * x0 + x1 * x1;
#pragma unroll
  for (int m = 1; m < 64; m <<= 1) ss += __shfl_xor(ss, m);
  float inv = rsqrtf(ss * (1.f / 128.f) + EPS_);
  x0 = x0 * inv * (wv[lane] + 1.f);
  x1 = x1 * inv * (wv[lane + 64] + 1.f);
  int pos = pos_ids[s];
  int i = lane & 31;
  float invf = expf(-logf(10000.f) * ((float)(2 * i) / 64.f));
  float f = (float)pos * invf;
  float c = cosf(f), sn = sinf(f);
  float p = __shfl_xor(x0, 32);
  x0 = (lane < 32) ? (x0 * c - p * sn) : (x0 * c + p * sn);
  dst[lane] = f2bf(x0 * scl);
  dst[lane + 64] = f2bf(x1 * scl);
}

// ---------------- V transpose: QKVf V-cols -> Vt[kh][128][S] bf16 ------
__global__ __launch_bounds__(256) void vtrans_kernel(const float* __restrict__ QKV,
                                                     short* __restrict__ Vt) {
  __shared__ __align__(16) float lt[64][68];
  const int t = threadIdx.x;
  const int s0 = blockIdx.x * 64, d0 = blockIdx.y * 64, kh = blockIdx.z;
  const float* src = QKV + (long)s0 * 6144 + 5120 + kh * 128 + d0;
#pragma unroll
  for (int i = 0; i < 4; ++i) {
    int idx = t + i * 256;
    int r = idx >> 4, c4 = (idx & 15) * 4;
    float4 v = *(const float4*)(src + (long)r * 6144 + c4);
    *(float4*)&lt[r][c4] = v;
  }
  __syncthreads();
  int d = t >> 2, seg = (t & 3) * 16;
  short* dst = Vt + ((long)kh * 128 + d0 + d) * S_ + s0 + seg;
  short8 a, b2;
#pragma unroll
  for (int j = 0; j < 8; ++j) a[j] = f2bf(lt[seg + j][d]);
#pragma unroll
  for (int j = 0; j < 8; ++j) b2[j] = f2bf(lt[seg + 8 + j][d]);
  *(short8*)dst = a;
  *(short8*)(dst + 8) = b2;
}

// ---------------- causal flash attention, GQA 4:1 ----------------------
__global__ __launch_bounds__(512, 2) void attn_kernel(const short* __restrict__ Qn,
    const short* __restrict__ Kn, const short* __restrict__ Vt,
    short* __restrict__ O) {
  __shared__ __align__(16) short Ks[64 * 128];
  __shared__ __align__(16) short Vs[128 * 64];
  __shared__ __align__(16) short Ps[8][16 * 64];
  const int t = threadIdx.x, w = t >> 6, lane = t & 63;
  const int b = blockIdx.x;
  const int h = b & 31, qt = 15 - (b >> 5);
  const int kh = h >> 2;
  const int q0 = qt * 128;
  const int l15 = lane & 15, lk = (lane >> 4) * 8;

  short8 qf[4];
  {
    const short* Qh = Qn + ((long)h * S_ + q0 + w * 16) * 128;
#pragma unroll
    for (int ks = 0; ks < 4; ++ks)
      qf[ks] = *(const short8*)(Qh + l15 * 128 + ks * 32 + lk);
  }
  f32x4 o[8];
#pragma unroll
  for (int nf = 0; nf < 8; ++nf) o[nf] = (f32x4){0.f, 0.f, 0.f, 0.f};
  float mrun[4], lrun[4];
#pragma unroll
  for (int r = 0; r < 4; ++r) { mrun[r] = -1e30f; lrun[r] = 0.f; }

  const short* Khp = Kn + (long)kh * S_ * 128;
  const short* Vtp = Vt + (long)kh * 128 * S_;

  const int krr = w * 8 + (lane >> 4);
  const int kc = lane & 15;
  const int vdd = w * 16 + (lane >> 3);
  const int vc = lane & 7;
  char* pw = (char*)Ps[w];
  const int mrow = (lane >> 4) * 4;

  for (int kv0 = 0; kv0 < q0 + 128; kv0 += 64) {
#pragma unroll
    for (int j = 0; j < 2; ++j) {
      int rr = krr + j * 4;
      __builtin_amdgcn_global_load_lds(
          (const AS1 void*)(Khp + (long)(kv0 + rr) * 128 + ((kc ^ (rr & 7)) * 8)),
          (AS3 void*)(Ks + (w * 8 + j * 4) * 128 + lane * 8), 16, 0, 0);
    }
#pragma unroll
    for (int j = 0; j < 2; ++j) {
      int d = vdd + j * 8;
      __builtin_amdgcn_global_load_lds(
          (const AS1 void*)(Vtp + (long)d * S_ + kv0 + ((vc ^ (d & 7)) * 8)),
          (AS3 void*)(Vs + (w * 16 + j * 8) * 64 + lane * 8), 16, 0, 0);
    }
    __syncthreads();

    const bool active = (kv0 <= q0 + w * 16 + 15);
    if (active) {
      f32x4 sc[4];
#pragma unroll
      for (int ni = 0; ni < 4; ++ni) sc[ni] = (f32x4){0.f, 0.f, 0.f, 0.f};
#pragma unroll
      for (int ks = 0; ks < 4; ++ks)
#pragma unroll
        for (int ni = 0; ni < 4; ++ni) {
          int row = ni * 16 + l15;
          int bb = row * 256 + (ks * 32 + lk) * 2; bb ^= (row & 7) << 4;
          short8 kf = *(const short8*)((const char*)Ks + bb);
          sc[ni] = __builtin_amdgcn_mfma_f32_16x16x32_bf16(qf[ks], kf, sc[ni], 0, 0, 0);
        }
      if (kv0 + 64 > q0 + w * 16) {
#pragma unroll
        for (int ni = 0; ni < 4; ++ni)
#pragma unroll
          for (int r = 0; r < 4; ++r) {
            int qm = q0 + w * 16 + mrow + r;
            int kcol = kv0 + ni * 16 + l15;
            if (kcol > qm) sc[ni][r] = -1e30f;
          }
      }
      short pb[4][4];
#pragma unroll
      for (int r = 0; r < 4; ++r) {
        float mx = fmaxf(fmaxf(sc[0][r], sc[1][r]), fmaxf(sc[2][r], sc[3][r]));
        mx = fmaxf(mx, __shfl_xor(mx, 1));
        mx = fmaxf(mx, __shfl_xor(mx, 2));
        mx = fmaxf(mx, __shfl_xor(mx, 4));
        mx = fmaxf(mx, __shfl_xor(mx, 8));
        float mnew = fmaxf(mrun[r], mx);
        float scale = expf(mrun[r] - mnew);
        mrun[r] = mnew;
        float ssum = 0.f;
#pragma unroll
        for (int ni = 0; ni < 4; ++ni) {
          float p = expf(sc[ni][r] - mnew);
          ssum += p;
          pb[ni][r] = f2bf(p);
        }
        ssum += __shfl_xor(ssum, 1);
        ssum += __shfl_xor(ssum, 2);
        ssum += __shfl_xor(ssum, 4);
        ssum += __shfl_xor(ssum, 8);
        lrun[r] = lrun[r] * scale + ssum;
#pragma unroll
        for (int nf = 0; nf < 8; ++nf) o[nf][r] *= scale;
      }
#pragma unroll
      for (int ni = 0; ni < 4; ++ni)
#pragma unroll
        for (int r = 0; r < 4; ++r) {
          int m = mrow + r;
          int bb = m * 128 + (ni * 16 + l15) * 2; bb ^= (m & 7) << 4;
          *(short*)(pw + bb) = pb[ni][r];
        }
#pragma unroll
      for (int ks2 = 0; ks2 < 2; ++ks2) {
        int bp = l15 * 128 + (ks2 * 32 + lk) * 2; bp ^= (l15 & 7) << 4;
        short8 pf = *(const short8*)(pw + bp);
#pragma unroll
        for (int nf = 0; nf < 8; ++nf) {
          int bv = (nf * 16 + l15) * 128 + (ks2 * 32 + lk) * 2; bv ^= (l15 & 7) << 4;
          short8 vf = *(const short8*)((const char*)Vs + bv);
          o[nf] = __builtin_amdgcn_mfma_f32_16x16x32_bf16(pf, vf, o[nf], 0, 0, 0);
        }
      }
    }
    __syncthreads();
  }
#pragma unroll
  for (int r = 0; r < 4; ++r) {
    float invl = 1.f / lrun[r];
    int m = q0 + w * 16 + mrow + r;
#pragma unroll
    for (int nf = 0; nf < 8; ++nf)
      O[(long)m * 4096 + h * 128 + nf * 16 + l15] = f2bf(o[nf][r] * invl);
  }
}

// ---------------- launch -----------------------------------------------
extern "C" void kernel_launch(void* const* d_in, const int* in_sizes, int n_in,
                              void* d_out, int out_size, void* d_ws, size_t ws_size,
                              hipStream_t stream) {
  const float* hidden = (const float*)d_in[0];
  const float* Wq = (const float*)d_in[1];
  const float* Wk = (const float*)d_in[2];
  const float* Wv = (const float*)d_in[3];
  const float* Wo = (const float*)d_in[4];
  const float* qw = (const float*)d_in[5];
  const float* kw = (const float*)d_in[6];
  const int* pos = (const int*)d_in[7];
  float* out = (float*)d_out;

  char* ws = (char*)d_ws;
  short* hid_bf  = (short*)(ws + 0);              // 16 MB (dead after GEMM1)
  short* Wqkv_bf = (short*)(ws + 16777216L);      // 48 MB
  short* Wo_bf   = (short*)(ws + 67108864L);      // 32 MB
  float* QKVf    = (float*)(ws + 100663296L);     // 48 MB
  short* Qn      = (short*)(ws + 150994944L);     // 16 MB
  short* Kn      = (short*)(ws + 167772160L);     // 4 MB
  short* Vt      = (short*)(ws + 171966464L);     // 4 MB
  short* AO      = hid_bf;                        // alias

  (void)hipFuncSetAttribute((const void*)gemm8_bt<3>,
                            hipFuncAttributeMaxDynamicSharedMemorySize, 114688);
  (void)hipFuncSetAttribute((const void*)gemm8_bt<2>,
                            hipFuncAttributeMaxDynamicSharedMemorySize, 98304);

  auto cast = [&](const float* s_, short* d_, long n) {
    int n4 = (int)(n / 4);
    cast_bf16_kernel<<<(n4 + 255) / 256, 256, 0, stream>>>((const float4*)s_, (short4v*)d_, n4);
  };
  cast(hidden, hid_bf, (long)S_ * HID_);
  cast(Wq, Wqkv_bf, (long)4096 * 4096);
  cast(Wk, Wqkv_bf + (long)4096 * 4096, (long)1024 * 4096);
  cast(Wv, Wqkv_bf + (long)5120 * 4096, (long)1024 * 4096);
  cast(Wo, Wo_bf, (long)4096 * 4096);

  // QKV = hidden @ [Wq;Wk;Wv]^T : M=2048, N=6144, K=4096 -> 8 x 32 = 256 blocks
  gemm8_bt<3><<<dim3(256), 512, 114688, stream>>>(hid_bf, Wqkv_bf, QKVf, S_, 6144, HID_);

  normrope_kernel<<<(S_ * (NH + NKH)) / 4, 256, 0, stream>>>(QKVf, pos, qw, kw, Qn, Kn);
  vtrans_kernel<<<dim3(S_ / 64, 2, NKH), 256, 0, stream>>>(QKVf, Vt);
  attn_kernel<<<dim3(512), 512, 0, stream>>>(Qn, Kn, Vt, AO);

  // out = AO @ Wo^T : M=2048, N=4096, K=4096 -> 8 x 32 = 256 blocks
  gemm8_bt<2><<<dim3(256), 512, 98304, stream>>>(AO, Wo_bf, out, S_, HID_, HID_);
}